// Round 6
// baseline (335.460 us; speedup 1.0000x reference)
//
#include <hip/hip_runtime.h>

#define NCLS 100
#define DIM  512
#define EPSV 1e-8f

#define DSPL  4            // dim splits of 128 dims per block
#define CH    192          // row chunks -> grid 4x192 = 768 blocks = 3/CU (51.2 KB LDS)
#define BATCH 16
#define SCALE 262144.0f    // 2^18 fixed-point scale

// ---------------- segment-sum: LDS int atomics -> global int atomics ----------------
// Block (ds, ch) covers dims [ds*128, ds*128+128) of row chunk ch. Lane owns dims
// (ds*128+lane) and (ds*128+64+lane): two 256 B coalesced dword loads per row,
// two conflict-free ds_add_u32 (banks = lane%32, 2 lanes/bank = free).
// Fixed-point int accumulation is exact/order-independent -> the block flushes its
// LDS acc straight into global S[NCLS*DIM] with atomics: no partial buffer, no
// finalize reduction, fully deterministic. Counts are not needed at all: cosine is
// scale-invariant, so cos(f, mean) == cos(f, S).
__global__ __launch_bounds__(256, 4) void sum_kernel(const float* __restrict__ feat,
                                                     const int* __restrict__ label,
                                                     int* __restrict__ S, int n) {
    __shared__ int acc[NCLS * 128];
    const int tid = threadIdx.x;
    const int ds  = blockIdx.x;
    const int ch  = blockIdx.y;

    for (int i = tid; i < NCLS * 128; i += 256) acc[i] = 0;
    __syncthreads();

    const int rpc  = (n + CH - 1) / CH;            // 521
    const int rows = min(rpc, n - ch * rpc);
    const int r0   = ch * rpc;
    const int w    = tid >> 6;
    const int lane = tid & 63;
    const int lo   = (rows * w) >> 2;
    const int hi   = (rows * (w + 1)) >> 2;
    const float* f0 = feat + (size_t)ds * 128 + lane;   // plane0; plane1 at +64

    int r = lo;
    for (; r + BATCH <= hi; r += BATCH) {
        // 32 coalesced 256 B loads in flight + 1 label dword (lanes 0..15)
        float va[BATCH], vb[BATCH];
        #pragma unroll
        for (int k = 0; k < BATCH; ++k) {
            const float* p = f0 + (size_t)(r0 + r + k) * DIM;
            va[k] = p[0];
            vb[k] = p[64];
        }
        const int myl = label[r0 + r + (lane & (BATCH - 1))];
        #pragma unroll
        for (int k = 0; k < BATCH; ++k) {
            const int c = __shfl(myl, k, 64);           // wave-uniform class
            int* a = &acc[c * 128 + lane];
            atomicAdd(a,      __float2int_rn(va[k] * SCALE));
            atomicAdd(a + 64, __float2int_rn(vb[k] * SCALE));
        }
    }
    for (; r < hi; ++r) {                               // tail rows
        const int c = label[r0 + r];
        const float* p = f0 + (size_t)(r0 + r) * DIM;
        int* a = &acc[c * 128 + lane];
        atomicAdd(a,      __float2int_rn(p[0]  * SCALE));
        atomicAdd(a + 64, __float2int_rn(p[64] * SCALE));
    }
    __syncthreads();

    // flush: acc[c*128 + j] -> S[c*DIM + ds*128 + j], exact int atomics
    for (int i = tid; i < NCLS * 128; i += 256) {
        const int c = i >> 7;
        const int j = i & 127;
        atomicAdd(&S[(size_t)c * DIM + ds * 128 + j], acc[i]);
    }
}

// ---------------- normalize: mhat[c] = S / ||S|| ----------------
// Scale and count cancel in cosine, so the unit vector is all we need.
__global__ __launch_bounds__(512) void norm_kernel(const int* __restrict__ S,
                                                   float* __restrict__ mhat) {
    const int c = blockIdx.x;
    const int t = threadIdx.x;
    const float v = (float)S[(size_t)c * DIM + t];

    float ss = v * v;
    #pragma unroll
    for (int o = 32; o; o >>= 1) ss += __shfl_down(ss, o, 64);
    __shared__ float red[8];
    if ((t & 63) == 0) red[t >> 6] = ss;
    __syncthreads();
    float tot = 0.f;
    #pragma unroll
    for (int k = 0; k < 8; ++k) tot += red[k];
    const float q = (tot > 0.f) ? (1.0f / sqrtf(tot)) : 0.0f;
    mhat[(size_t)c * DIM + t] = v * q;
}

// ---------------- cosine: 16 lanes per row, 4 rows per wave ----------------
__global__ __launch_bounds__(256) void cos_kernel(const float* __restrict__ feat,
                                                  const int* __restrict__ label,
                                                  const float* __restrict__ mhat,
                                                  float* __restrict__ out, int n) {
    const int lane = threadIdx.x & 63;
    const int wv   = threadIdx.x >> 6;
    const int cl   = lane >> 4;
    const int t    = lane & 15;

    const int row = blockIdx.x * 16 + wv * 4 + cl;
    const bool ok = row < n;
    const int rr = ok ? row : (n - 1);

    const int c = label[rr];
    const float4* f4 = (const float4*)(feat + (size_t)rr * DIM);
    const float4* m4 = (const float4*)(mhat + (size_t)c  * DIM);

    float4 a[8], b[8];
    #pragma unroll
    for (int j = 0; j < 8; ++j) a[j] = f4[t + 16 * j];
    #pragma unroll
    for (int j = 0; j < 8; ++j) b[j] = m4[t + 16 * j];

    float dot = 0.0f, nf = 0.0f;
    #pragma unroll
    for (int j = 0; j < 8; ++j) {
        dot += a[j].x * b[j].x + a[j].y * b[j].y + a[j].z * b[j].z + a[j].w * b[j].w;
        nf  += a[j].x * a[j].x + a[j].y * a[j].y + a[j].z * a[j].z + a[j].w * a[j].w;
    }

    #pragma unroll
    for (int off = 8; off; off >>= 1) {
        dot += __shfl_xor(dot, off, 64);
        nf  += __shfl_xor(nf,  off, 64);
    }
    if (t == 0 && ok) {
        out[row] = dot / fmaxf(sqrtf(nf), EPSV);
    }
}

extern "C" void kernel_launch(void* const* d_in, const int* in_sizes, int n_in,
                              void* d_out, int out_size, void* d_ws, size_t ws_size,
                              hipStream_t stream) {
    const float* feat  = (const float*)d_in[0];
    const int*   label = (const int*)d_in[1];
    float*       out   = (float*)d_out;
    const int n = in_sizes[0] / DIM;   // 100000

    // ws layout (4 B units): S ints [NCLS*DIM] | mhat floats [NCLS*DIM]
    int*   S    = (int*)d_ws;
    float* mhat = (float*)(S + NCLS * DIM);

    hipMemsetAsync(S, 0, NCLS * DIM * sizeof(int), stream);   // 200 KB, ~2 us

    dim3 sg(DSPL, CH);                 // 768 blocks x 256 threads = 3/CU
    sum_kernel<<<sg, 256, 0, stream>>>(feat, label, S, n);
    norm_kernel<<<NCLS, 512, 0, stream>>>(S, mhat);
    cos_kernel<<<(n + 15) / 16, 256, 0, stream>>>(feat, label, mhat, out, n);
}

// Round 7
// 327.163 us; speedup vs baseline: 1.0254x; 1.0254x over previous
//
#include <hip/hip_runtime.h>

#define NCLS 100
#define DIM  512
#define EPSV 1e-8f

#define DSPL  8            // dim splits of 64; lane owns 1 dim
#define CH    192          // row chunks -> grid 8x192 = 1536 blocks = 6/CU (25.6 KB LDS)
#define BATCH 16
#define SCALE 262144.0f    // 2^18 fixed-point scale

// ---------------- segment-sum: int LDS atomics, double-buffered loads ----------------
// Block (ds, ch) covers dims [ds*64, ds*64+64) of row chunk ch; 4 waves split the
// rows. Lane owns one dim: per row one coalesced 256 B load + one ds_add_u32
// (bank = lane%32, 2 lanes/bank = free). Fixed-point int accumulation is exact and
// order-independent -> block flushes straight into global S with atomics
// (deterministic, no partial buffer). Counts cancel in cosine -> no histogram.
// The row loop is software-pipelined: batch b+1's 16 value loads + label dword are
// issued BEFORE batch b's shfl/cvt/ds_add, so ~32 loads/wave stay in flight and,
// at 24 waves/CU, HBM latency is covered (round-4/6 drained vmcnt(0) per batch
// with 12 waves/CU -- the measured ~120 us stall).
__global__ __launch_bounds__(256, 6) void sum_kernel(const float* __restrict__ feat,
                                                     const int* __restrict__ label,
                                                     int* __restrict__ S, int n) {
    __shared__ int acc[NCLS * 64];
    const int tid = threadIdx.x;
    const int ds  = blockIdx.x;
    const int ch  = blockIdx.y;

    for (int i = tid; i < NCLS * 64; i += 256) acc[i] = 0;
    __syncthreads();

    const int rpc  = (n + CH - 1) / CH;            // 521
    const int r0   = ch * rpc;
    const int rows = min(rpc, n - r0);
    const int w    = tid >> 6;
    const int lane = tid & 63;
    const int lo   = (rows * w) / 4;
    const int hi   = (rows * (w + 1)) / 4;
    const float* fb = feat + (size_t)ds * 64 + lane;

    float vA[BATCH], vB[BATCH];
    int mylA = 0, mylB = 0;

    auto loadA = [&](int rb) {
        mylA = label[r0 + rb + (lane & (BATCH - 1))];
        #pragma unroll
        for (int k = 0; k < BATCH; ++k)
            vA[k] = fb[(size_t)(r0 + rb + k) * DIM];
    };
    auto loadB = [&](int rb) {
        mylB = label[r0 + rb + (lane & (BATCH - 1))];
        #pragma unroll
        for (int k = 0; k < BATCH; ++k)
            vB[k] = fb[(size_t)(r0 + rb + k) * DIM];
    };
    auto proc = [&](int myl, float (&v)[BATCH]) {
        #pragma unroll
        for (int k = 0; k < BATCH; ++k) {
            const int c = __shfl(myl, k, 64);           // wave-uniform class
            atomicAdd(&acc[c * 64 + lane], __float2int_rn(v[k] * SCALE));
        }
    };

    const int nb = (hi - lo) / BATCH;
    if (nb > 0) {
        loadA(lo);
        for (int ib = 0; ib + 1 < nb; ++ib) {
            if (ib & 1) { loadA(lo + (ib + 1) * BATCH); proc(mylB, vB); }
            else        { loadB(lo + (ib + 1) * BATCH); proc(mylA, vA); }
        }
        if ((nb - 1) & 1) proc(mylB, vB); else proc(mylA, vA);
    }
    for (int r = lo + nb * BATCH; r < hi; ++r) {        // tail rows
        const int c = label[r0 + r];
        atomicAdd(&acc[c * 64 + lane], __float2int_rn(fb[(size_t)(r0 + r) * DIM] * SCALE));
    }
    __syncthreads();

    // flush: acc[c*64 + j] -> S[c*DIM + ds*64 + j], exact int atomics
    for (int i = tid; i < NCLS * 64; i += 256)
        atomicAdd(&S[(size_t)(i >> 6) * DIM + ds * 64 + (i & 63)], acc[i]);
}

// ---------------- normalize: mhat[c] = S / ||S|| ----------------
// Scale and count cancel in cosine, so the unit vector is all we need.
__global__ __launch_bounds__(512) void norm_kernel(const int* __restrict__ S,
                                                   float* __restrict__ mhat) {
    const int c = blockIdx.x;
    const int t = threadIdx.x;
    const float v = (float)S[(size_t)c * DIM + t];

    float ss = v * v;
    #pragma unroll
    for (int o = 32; o; o >>= 1) ss += __shfl_down(ss, o, 64);
    __shared__ float red[8];
    if ((t & 63) == 0) red[t >> 6] = ss;
    __syncthreads();
    float tot = 0.f;
    #pragma unroll
    for (int k = 0; k < 8; ++k) tot += red[k];
    const float q = (tot > 0.f) ? (1.0f / sqrtf(tot)) : 0.0f;
    mhat[(size_t)c * DIM + t] = v * q;
}

// ---------------- cosine: 16 lanes per row, 4 rows per wave ----------------
__global__ __launch_bounds__(256) void cos_kernel(const float* __restrict__ feat,
                                                  const int* __restrict__ label,
                                                  const float* __restrict__ mhat,
                                                  float* __restrict__ out, int n) {
    const int lane = threadIdx.x & 63;
    const int wv   = threadIdx.x >> 6;
    const int cl   = lane >> 4;
    const int t    = lane & 15;

    const int row = blockIdx.x * 16 + wv * 4 + cl;
    const bool ok = row < n;
    const int rr = ok ? row : (n - 1);

    const int c = label[rr];
    const float4* f4 = (const float4*)(feat + (size_t)rr * DIM);
    const float4* m4 = (const float4*)(mhat + (size_t)c  * DIM);

    float4 a[8], b[8];
    #pragma unroll
    for (int j = 0; j < 8; ++j) a[j] = f4[t + 16 * j];
    #pragma unroll
    for (int j = 0; j < 8; ++j) b[j] = m4[t + 16 * j];

    float dot = 0.0f, nf = 0.0f;
    #pragma unroll
    for (int j = 0; j < 8; ++j) {
        dot += a[j].x * b[j].x + a[j].y * b[j].y + a[j].z * b[j].z + a[j].w * b[j].w;
        nf  += a[j].x * a[j].x + a[j].y * a[j].y + a[j].z * a[j].z + a[j].w * a[j].w;
    }

    #pragma unroll
    for (int off = 8; off; off >>= 1) {
        dot += __shfl_xor(dot, off, 64);
        nf  += __shfl_xor(nf,  off, 64);
    }
    if (t == 0 && ok) {
        out[row] = dot / fmaxf(sqrtf(nf), EPSV);
    }
}

extern "C" void kernel_launch(void* const* d_in, const int* in_sizes, int n_in,
                              void* d_out, int out_size, void* d_ws, size_t ws_size,
                              hipStream_t stream) {
    const float* feat  = (const float*)d_in[0];
    const int*   label = (const int*)d_in[1];
    float*       out   = (float*)d_out;
    const int n = in_sizes[0] / DIM;   // 100000

    // ws layout (4 B units): S ints [NCLS*DIM] | mhat floats [NCLS*DIM]
    int*   S    = (int*)d_ws;
    float* mhat = (float*)(S + NCLS * DIM);

    hipMemsetAsync(S, 0, NCLS * DIM * sizeof(int), stream);   // 200 KB, ~2 us

    dim3 sg(DSPL, CH);                 // 1536 blocks x 256 threads = 6/CU
    sum_kernel<<<sg, 256, 0, stream>>>(feat, label, S, n);
    norm_kernel<<<NCLS, 512, 0, stream>>>(S, mhat);
    cos_kernel<<<(n + 15) / 16, 256, 0, stream>>>(feat, label, mhat, out, n);
}